// Round 11
// baseline (199.791 us; speedup 1.0000x reference)
//
#include <hip/hip_runtime.h>

#define SPLINE_OFF 25165824   // splines output offset (6120 floats follow)
#define STEP_F (1.0f/9.0f)

typedef float f32x4 __attribute__((ext_vector_type(4)));

// ---------------------------------------------------------------------------
// Resize: jax.image.resize bilinear antialias 1024->256 (scale .25), separable
// triangle kernel {1,3,5,7,7,5,3,1}/8 at stride 4, renormalized at edges.
// Each block produces FOUR output rows of one plane (reads 20 rows once).
// Block 0 zeroes the c345 barrier/finale counters (stream-ordered earlier).
// ---------------------------------------------------------------------------
__global__ __launch_bounds__(256) void resize_k(const float* __restrict__ x,
                                                float* __restrict__ sm,
                                                unsigned* __restrict__ ctr) {
    __shared__ float vs[4][1024];
    const int blk = blockIdx.x;          // 24*64
    const int plane = blk >> 6;
    const int orA = (blk & 63) * 4;      // output rows orA..orA+3
    const int t = threadIdx.x;
    if (blk == 0 && t < 3) ctr[t] = 0u;

    const float W[8] = {0.125f,0.375f,0.625f,0.875f,0.875f,0.625f,0.375f,0.125f};
    const float* p = x + (size_t)plane * 1048576 + t * 4;
    const int rb = 4 * orA - 2;

    float acc[4][4];
    #pragma unroll
    for (int o = 0; o < 4; o++)
        #pragma unroll
        for (int c = 0; c < 4; c++) acc[o][c] = 0.f;

    if (rb >= 0 && rb + 19 <= 1023) {
        #pragma unroll
        for (int k = 0; k < 20; k++) {
            const float4 v = *(const float4*)(p + (size_t)(rb + k) * 1024);
            #pragma unroll
            for (int o = 0; o < 4; o++) {
                const int j = k - 4 * o;
                if (j >= 0 && j < 8) {
                    const float w = W[j] * 0.25f;
                    acc[o][0] = fmaf(v.x, w, acc[o][0]);
                    acc[o][1] = fmaf(v.y, w, acc[o][1]);
                    acc[o][2] = fmaf(v.z, w, acc[o][2]);
                    acc[o][3] = fmaf(v.w, w, acc[o][3]);
                }
            }
        }
    } else {
        #pragma unroll
        for (int o = 0; o < 4; o++) {
            const int r0 = 4 * (orA + o) - 2;
            float bx=0.f,by=0.f,bz=0.f,bw=0.f,wsum=0.f;
            #pragma unroll
            for (int k = 0; k < 8; k++) {
                const int r = r0 + k;
                if (r >= 0 && r < 1024) {
                    const float4 v = *(const float4*)(p + (size_t)r * 1024);
                    bx = fmaf(v.x, W[k], bx); by = fmaf(v.y, W[k], by);
                    bz = fmaf(v.z, W[k], bz); bw = fmaf(v.w, W[k], bw);
                    wsum += W[k];
                }
            }
            const float inv = 1.f / wsum;
            acc[o][0]=bx*inv; acc[o][1]=by*inv; acc[o][2]=bz*inv; acc[o][3]=bw*inv;
        }
    }
    #pragma unroll
    for (int o = 0; o < 4; o++) {
        vs[o][4*t+0]=acc[o][0]; vs[o][4*t+1]=acc[o][1];
        vs[o][4*t+2]=acc[o][2]; vs[o][4*t+3]=acc[o][3];
    }
    __syncthreads();

    const int c0 = 4 * t - 2;
    #pragma unroll
    for (int o = 0; o < 4; o++) {
        float a = 0.f;
        if (c0 >= 0 && c0 + 7 <= 1023) {
            #pragma unroll
            for (int k = 0; k < 8; k++)
                a = fmaf(vs[o][c0 + k], W[k] * 0.25f, a);
        } else {
            float wsum = 0.f;
            #pragma unroll
            for (int k = 0; k < 8; k++) {
                const int c = c0 + k;
                if (c >= 0 && c < 1024) { a = fmaf(vs[o][c], W[k], a); wsum += W[k]; }
            }
            a /= wsum;
        }
        sm[((size_t)plane * 256 + orA + o) * 256 + t] = a;
    }
}

// ---------------------------------------------------------------------------
// Direct 3x3 stride-2 VALID conv + bias + ReLU (conv1/conv2 only).
// STATS: block-reduced per-channel sum/sumsq -> unique partial slot.
// Grid: (NTOUT, B * COUT/2). Block: PIX threads (CISPLIT=1 here).
// ---------------------------------------------------------------------------
template<int CIN, int COUT, int INW, int OUTW, int CISPLIT, int PIX,
         int NTPREV, int NTOUT, bool INBN, bool STATS, bool WRITE>
__global__ __launch_bounds__(PIX * CISPLIT) void conv_k(
    const float* __restrict__ in, const float* __restrict__ w,
    const float* __restrict__ bias,
    const float* __restrict__ gam, const float* __restrict__ be,
    const float* __restrict__ pS, const float* __restrict__ pQ, float invN,
    float* __restrict__ out,
    float* __restrict__ pSo, float* __restrict__ pQo)
{
    constexpr int BLOCK = PIX * CISPLIT;
    constexpr int CPS = CIN / CISPLIT;
    constexpr int COG = COUT / 2;

    __shared__ float wsm[2][CIN * 9];
    __shared__ float scs[CIN], shs[CIN];
    __shared__ float wrow[2][CIN];
    __shared__ float cadd[2];
    __shared__ float part[CISPLIT][PIX][2];
    __shared__ float red[2][2][PIX / 64];
    __shared__ float sredS[BLOCK], sredQ[BLOCK];

    const int tid = threadIdx.x;
    const int p   = tid & (PIX - 1);
    const int cs  = tid / PIX;
    const int bc  = blockIdx.y;
    const int b   = bc / COG;
    const int co0 = (bc % COG) * 2;

    if constexpr (INBN) {
        constexpr int GRP = BLOCK / CIN;
        constexpr int TERMS = 8 * NTPREV;
        const int ci = tid % CIN;
        const int gi = tid / CIN;
        float s = 0.f, q = 0.f;
        for (int j = gi; j < TERMS; j += GRP) {
            const int bb = j / NTPREV, tl = j - bb * NTPREV;
            const int a = (bb * CIN + ci) * NTPREV + tl;
            s += pS[a]; q += pQ[a];
        }
        sredS[gi * CIN + ci] = s;
        sredQ[gi * CIN + ci] = q;
        __syncthreads();
        if (tid < CIN) {
            float ts = 0.f, tq = 0.f;
            #pragma unroll
            for (int g2 = 0; g2 < GRP; g2++) {
                ts += sredS[g2 * CIN + tid];
                tq += sredQ[g2 * CIN + tid];
            }
            const float m = ts * invN;
            const float v = tq * invN - m * m;
            const float sc = gam[tid] * rsqrtf(v + 1e-5f);
            scs[tid] = sc;
            shs[tid] = be[tid] - m * sc;
        }
        __syncthreads();
    }

    for (int i = tid; i < 2 * CIN * 9; i += BLOCK) {
        const int n = i / (CIN * 9), r = i - n * (CIN * 9), ci = r / 9;
        const float wv = w[(co0 + n) * CIN * 9 + r];
        wsm[n][r] = INBN ? wv * scs[ci] : wv;
    }
    if constexpr (INBN) {
        for (int i = tid; i < 2 * CIN; i += BLOCK) {
            const int n = i / CIN, ci = i - n * CIN;
            const float* wp = w + ((co0 + n) * CIN + ci) * 9;
            float s = 0.f;
            #pragma unroll
            for (int k = 0; k < 9; k++) s += wp[k];
            wrow[n][ci] = s;
        }
    }
    __syncthreads();
    if (tid < 2) {
        float c = bias[co0 + tid];
        if constexpr (INBN) {
            for (int ci = 0; ci < CIN; ci++) c = fmaf(wrow[tid][ci], shs[ci], c);
        }
        cadd[tid] = c;
    }
    __syncthreads();

    const int npix = OUTW * OUTW;
    const int pg = blockIdx.x * PIX + p;
    float a0 = 0.f, a1 = 0.f;
    if (pg < npix) {
        const int oh = pg / OUTW, ow = pg - oh * OUTW;
        const float* ib = in + ((size_t)(b * CIN) + cs * CPS) * (INW * INW)
                             + (size_t)(2 * oh) * INW + 2 * ow;
        #pragma unroll 4
        for (int ci = 0; ci < CPS; ci++) {
            const float* ip = ib + (size_t)ci * (INW * INW);
            const int cw = (cs * CPS + ci) * 9;
            #pragma unroll
            for (int kh = 0; kh < 3; kh++) {
                const float* r = ip + kh * INW;
                #pragma unroll
                for (int kw = 0; kw < 3; kw++) {
                    const float xv = r[kw];
                    a0 = fmaf(xv, wsm[0][cw + kh * 3 + kw], a0);
                    a1 = fmaf(xv, wsm[1][cw + kh * 3 + kw], a1);
                }
            }
        }
    }

    float v0 = 0.f, v1 = 0.f;
    if constexpr (CISPLIT > 1) {
        part[cs][p][0] = a0; part[cs][p][1] = a1;
        __syncthreads();
    }
    if (cs == 0) {
        float s0 = a0, s1 = a1;
        if constexpr (CISPLIT > 1) {
            #pragma unroll
            for (int q = 1; q < CISPLIT; q++) { s0 += part[q][p][0]; s1 += part[q][p][1]; }
        }
        if (pg < npix) {
            v0 = fmaxf(s0 + cadd[0], 0.f);
            v1 = fmaxf(s1 + cadd[1], 0.f);
            if constexpr (WRITE) {
                out[(size_t)(b * COUT + co0) * npix + pg] = v0;
                out[(size_t)(b * COUT + co0 + 1) * npix + pg] = v1;
            }
        }
    }

    if constexpr (STATS) {
        if (cs == 0) {
            float sA = v0, qA = v0 * v0, sB = v1, qB = v1 * v1;
            #pragma unroll
            for (int off = 32; off > 0; off >>= 1) {
                sA += __shfl_down(sA, off); qA += __shfl_down(qA, off);
                sB += __shfl_down(sB, off); qB += __shfl_down(qB, off);
            }
            if ((tid & 63) == 0) {
                red[0][0][tid >> 6] = sA; red[0][1][tid >> 6] = qA;
                red[1][0][tid >> 6] = sB; red[1][1][tid >> 6] = qB;
            }
        }
        __syncthreads();
        if (tid == 0) {
            float tsA = 0.f, tqA = 0.f, tsB = 0.f, tqB = 0.f;
            #pragma unroll
            for (int i = 0; i < PIX / 64; i++) {
                tsA += red[0][0][i]; tqA += red[0][1][i];
                tsB += red[1][0][i]; tqB += red[1][1][i];
            }
            pSo[(b * COUT + co0) * NTOUT + blockIdx.x] = tsA;
            pQo[(b * COUT + co0) * NTOUT + blockIdx.x] = tqA;
            pSo[(b * COUT + co0 + 1) * NTOUT + blockIdx.x] = tsB;
            pQo[(b * COUT + co0 + 1) * NTOUT + blockIdx.x] = tqB;
        }
    }
}

// ---------------------------------------------------------------------------
// Shared scratch for the fused conv3/conv4/conv5 phases (reused per phase).
// ---------------------------------------------------------------------------
struct S345 {
    float wsm[2][576];          // BN-folded weights (max CIN=64)
    float scs[64], shs[64];
    float wrow[2][64];
    float cadd[2];
    float part[512];            // flat [(cs*PIX+p)*2+n]
    float red[2][2][4];
    float sredS[256], sredQ[256];
};

// Relaxed-spin counter barrier (all 512 blocks co-resident: 2 blocks/CU).
__device__ __forceinline__ void gb_sync(unsigned* cnt, unsigned target) {
    __syncthreads();
    if (threadIdx.x == 0) {
        __threadfence();   // release this block's global writes
        __hip_atomic_fetch_add(cnt, 1u, __ATOMIC_RELAXED, __HIP_MEMORY_SCOPE_AGENT);
        while (__hip_atomic_load(cnt, __ATOMIC_RELAXED, __HIP_MEMORY_SCOPE_AGENT) < target)
            __builtin_amdgcn_s_sleep(2);
        __threadfence();   // acquire
    }
    __syncthreads();
}

// One conv layer item (same math as conv_k). bid in [0,512): tile=bid%NTOUT,
// bc=bid/NTOUT. STATS always on; WRITE optional.
template<int CIN, int COUT, int INW, int OUTW, int CISPLIT, int PIX,
         int NTPREV, int NTOUT, bool WRITE>
__device__ __forceinline__ void phase345(
    S345& s,
    const float* __restrict__ in, const float* __restrict__ w,
    const float* __restrict__ bias, const float* __restrict__ gam,
    const float* __restrict__ be, const float* __restrict__ pS,
    const float* __restrict__ pQ, float invN,
    float* __restrict__ out, float* __restrict__ pSo, float* __restrict__ pQo,
    int bid, int tid)
{
    constexpr int BLOCK = 256;
    constexpr int CPS = CIN / CISPLIT;
    constexpr int COG = COUT / 2;
    const int p    = tid & (PIX - 1);
    const int cs   = tid / PIX;
    const int tile = bid % NTOUT;
    const int bc   = bid / NTOUT;
    const int b    = bc / COG;
    const int co0  = (bc % COG) * 2;

    // BN of previous layer from its partials
    {
        constexpr int GRP = BLOCK / CIN;
        constexpr int TERMS = 8 * NTPREV;
        const int ci = tid % CIN;
        const int gi = tid / CIN;
        float sv = 0.f, qv = 0.f;
        for (int j = gi; j < TERMS; j += GRP) {
            const int bb = j / NTPREV, tl = j - bb * NTPREV;
            const int a = (bb * CIN + ci) * NTPREV + tl;
            sv += pS[a]; qv += pQ[a];
        }
        s.sredS[gi * CIN + ci] = sv;
        s.sredQ[gi * CIN + ci] = qv;
        __syncthreads();
        if (tid < CIN) {
            float ts = 0.f, tq = 0.f;
            #pragma unroll
            for (int g2 = 0; g2 < GRP; g2++) {
                ts += s.sredS[g2 * CIN + tid];
                tq += s.sredQ[g2 * CIN + tid];
            }
            const float m = ts * invN;
            const float v = tq * invN - m * m;
            const float sc = gam[tid] * rsqrtf(v + 1e-5f);
            s.scs[tid] = sc;
            s.shs[tid] = be[tid] - m * sc;
        }
        __syncthreads();
    }

    for (int i = tid; i < 2 * CIN * 9; i += BLOCK) {
        const int n = i / (CIN * 9), r = i - n * (CIN * 9), ci = r / 9;
        s.wsm[n][r] = w[(co0 + n) * CIN * 9 + r] * s.scs[ci];
    }
    for (int i = tid; i < 2 * CIN; i += BLOCK) {
        const int n = i / CIN, ci = i - n * CIN;
        const float* wp = w + ((co0 + n) * CIN + ci) * 9;
        float sv = 0.f;
        #pragma unroll
        for (int k = 0; k < 9; k++) sv += wp[k];
        s.wrow[n][ci] = sv;
    }
    __syncthreads();
    if (tid < 2) {
        float c = bias[co0 + tid];
        for (int ci = 0; ci < CIN; ci++) c = fmaf(s.wrow[tid][ci], s.shs[ci], c);
        s.cadd[tid] = c;
    }
    __syncthreads();

    const int npix = OUTW * OUTW;
    const int pg = tile * PIX + p;
    float a0 = 0.f, a1 = 0.f;
    if (pg < npix) {
        const int oh = pg / OUTW, ow = pg - oh * OUTW;
        const float* ib = in + ((size_t)(b * CIN) + cs * CPS) * (INW * INW)
                             + (size_t)(2 * oh) * INW + 2 * ow;
        #pragma unroll 4
        for (int ci = 0; ci < CPS; ci++) {
            const float* ip = ib + (size_t)ci * (INW * INW);
            const int cw = (cs * CPS + ci) * 9;
            #pragma unroll
            for (int kh = 0; kh < 3; kh++) {
                const float* r = ip + kh * INW;
                #pragma unroll
                for (int kw = 0; kw < 3; kw++) {
                    const float xv = r[kw];
                    a0 = fmaf(xv, s.wsm[0][cw + kh * 3 + kw], a0);
                    a1 = fmaf(xv, s.wsm[1][cw + kh * 3 + kw], a1);
                }
            }
        }
    }

    float v0 = 0.f, v1 = 0.f;
    if constexpr (CISPLIT > 1) {
        s.part[(cs * PIX + p) * 2 + 0] = a0;
        s.part[(cs * PIX + p) * 2 + 1] = a1;
        __syncthreads();
    }
    if (cs == 0) {
        float s0 = a0, s1 = a1;
        if constexpr (CISPLIT > 1) {
            #pragma unroll
            for (int q = 1; q < CISPLIT; q++) {
                s0 += s.part[(q * PIX + p) * 2 + 0];
                s1 += s.part[(q * PIX + p) * 2 + 1];
            }
        }
        if (pg < npix) {
            v0 = fmaxf(s0 + s.cadd[0], 0.f);
            v1 = fmaxf(s1 + s.cadd[1], 0.f);
            if constexpr (WRITE) {
                out[(size_t)(b * COUT + co0) * npix + pg] = v0;
                out[(size_t)(b * COUT + co0 + 1) * npix + pg] = v1;
            }
        }
        float sA = v0, qA = v0 * v0, sB = v1, qB = v1 * v1;
        #pragma unroll
        for (int off = 32; off > 0; off >>= 1) {
            sA += __shfl_down(sA, off); qA += __shfl_down(qA, off);
            sB += __shfl_down(sB, off); qB += __shfl_down(qB, off);
        }
        if ((tid & 63) == 0) {
            s.red[0][0][tid >> 6] = sA; s.red[0][1][tid >> 6] = qA;
            s.red[1][0][tid >> 6] = sB; s.red[1][1][tid >> 6] = qB;
        }
    }
    __syncthreads();
    if (tid == 0) {
        float tsA = 0.f, tqA = 0.f, tsB = 0.f, tqB = 0.f;
        #pragma unroll
        for (int i = 0; i < PIX / 64; i++) {
            tsA += s.red[0][0][i]; tqA += s.red[0][1][i];
            tsB += s.red[1][0][i]; tqB += s.red[1][1][i];
        }
        pSo[(b * COUT + co0) * NTOUT + tile] = tsA;
        pQo[(b * COUT + co0) * NTOUT + tile] = tqA;
        pSo[(b * COUT + co0 + 1) * NTOUT + tile] = tsB;
        pQo[(b * COUT + co0 + 1) * NTOUT + tile] = tqB;
    }
}

// ---------------------------------------------------------------------------
// Fused conv3 -> conv4 -> conv5 -> fc/spline tail. 512 blocks x 256 threads,
// exactly 1 item per block per phase (parallelism preserved); two relaxed-
// spin barriers; wait-free last-block finale for the fc tail.
// ---------------------------------------------------------------------------
__global__ __launch_bounds__(256) void c345_k(
    const float* __restrict__ h2,
    const float* __restrict__ w3, const float* __restrict__ b3,
    const float* __restrict__ g2, const float* __restrict__ be2,
    const float* __restrict__ pS2, const float* __restrict__ pQ2,
    float* __restrict__ h3, float* __restrict__ pS3, float* __restrict__ pQ3,
    const float* __restrict__ w4, const float* __restrict__ b4,
    const float* __restrict__ g3, const float* __restrict__ be3,
    float* __restrict__ h4, float* __restrict__ pS4, float* __restrict__ pQ4,
    const float* __restrict__ w5, const float* __restrict__ b5,
    const float* __restrict__ g4, const float* __restrict__ be4,
    float* __restrict__ pS5, float* __restrict__ pQ5,
    const float* __restrict__ g5, const float* __restrict__ be5,
    const float* __restrict__ fc1w, const float* __restrict__ fc1b,
    const float* __restrict__ fc2w, const float* __restrict__ fc2b,
    float* __restrict__ coeff_out, float* __restrict__ splines_out,
    unsigned* __restrict__ ctr)
{
    __shared__ S345 s;
    __shared__ unsigned lastFlag;
    __shared__ float fsc5[128], fsh5[128];
    __shared__ float fch[1024], fh1[1024];
    __shared__ float fysn[240];
    __shared__ float fcoef[24][36];

    const int bid = blockIdx.x;
    const int tid = threadIdx.x;

    // conv3: 16->32, 63->31 (BN2 from 16-tile partials; 4 tiles out)
    phase345<16, 32, 63, 31, 1, 256, 16, 4, true>(
        s, h2, w3, b3, g2, be2, pS2, pQ2, 1.0f / 31752.0f,
        h3, pS3, pQ3, bid, tid);
    gb_sync(&ctr[0], 512u);

    // conv4: 32->64, 31->15 (BN3 from 4-tile partials; ci-split 2; 2 tiles)
    phase345<32, 64, 31, 15, 2, 128, 4, 2, true>(
        s, h3, w4, b4, g3, be3, pS3, pQ3, 1.0f / 7688.0f,
        h4, pS4, pQ4, bid, tid);
    gb_sync(&ctr[1], 512u);

    // conv5: 64->128, 15->7 (BN4 from 2-tile partials; ci-split 4; stats only)
    phase345<64, 128, 15, 7, 4, 64, 2, 1, false>(
        s, h4, w5, b5, g4, be4, pS4, pQ4, 1.0f / 1800.0f,
        nullptr, pS5, pQ5, bid, tid);

    // wait-free last-block finale
    __syncthreads();
    if (tid == 0) {
        __threadfence();
        unsigned old = atomicAdd(&ctr[2], 1u);
        lastFlag = (old == 511u) ? 1u : 0u;
    }
    __syncthreads();
    if (lastFlag == 0u) return;
    __threadfence();

    const int t = tid;
    if (t < 128) {
        float sv = 0.f, qv = 0.f;
        #pragma unroll
        for (int bb = 0; bb < 8; bb++) { sv += pS5[bb * 128 + t]; qv += pQ5[bb * 128 + t]; }
        float m = sv * (1.f / 392.f);
        float v = qv * (1.f / 392.f) - m * m;
        float sc = g5[t] * rsqrtf(v + 1e-5f);
        fsc5[t] = sc;
        fsh5[t] = be5[t] - m * sc;
    }
    __syncthreads();

    for (int i = t; i < 1024; i += 256) {
        int c = i & 127;
        fch[i] = fmaf(fsc5[c], pS5[i] * (1.f / 49.f), fsh5[c]);
    }
    __syncthreads();

    for (int i = t; i < 1024; i += 256) {
        int bb = i >> 7, j = i & 127;
        float acc = fc1b[j];
        for (int c = 0; c < 128; c++)
            acc = fmaf(fch[(bb << 7) + c], fc1w[(j << 7) + c], acc);
        fh1[i] = fmaxf(acc, 0.f);
    }
    __syncthreads();

    if (t < 240) {
        int bb = t / 30, k = t % 30;
        float acc = fc2b[k];
        for (int j = 0; j < 128; j++)
            acc = fmaf(fh1[(bb << 7) + j], fc2w[(k << 7) + j], acc);
        fysn[t] = acc + (float)(k % 10) * STEP_F;
    }
    __syncthreads();

    if (t < 24) {
        float y[10];
        #pragma unroll
        for (int i = 0; i < 10; i++) y[i] = fysn[t * 10 + i];
        float rhs[9], cp[9], dp[9];
        #pragma unroll
        for (int i = 1; i <= 8; i++)
            rhs[i] = 486.f * (y[i - 1] - 2.f * y[i] + y[i + 1]);
        cp[1] = 0.25f; dp[1] = rhs[1] * 0.25f;
        #pragma unroll
        for (int i = 2; i <= 8; i++) {
            float m = 1.f / (4.f - cp[i - 1]);
            cp[i] = m;
            dp[i] = (rhs[i] - dp[i - 1]) * m;
        }
        float M[10];
        M[0] = 0.f; M[9] = 0.f;
        M[8] = dp[8];
        #pragma unroll
        for (int i = 7; i >= 1; i--) M[i] = dp[i] - cp[i] * M[i + 1];
        #pragma unroll
        for (int i = 0; i < 9; i++) {
            float a = (M[i + 1] - M[i]) * 1.5f;
            float bb2 = M[i] * 0.5f;
            float cc = (y[i + 1] - y[i]) * 9.f - (M[i + 1] + 2.f * M[i]) * (STEP_F / 6.f);
            float dd = y[i];
            fcoef[t][i] = a; fcoef[t][9 + i] = bb2; fcoef[t][18 + i] = cc; fcoef[t][27 + i] = dd;
            coeff_out[t * 36 + i] = a;
            coeff_out[t * 36 + 9 + i] = bb2;
            coeff_out[t * 36 + 18 + i] = cc;
            coeff_out[t * 36 + 27 + i] = dd;
        }
    }
    __syncthreads();

    for (int i = t; i < 24 * 255; i += 256) {
        int bc2 = i / 255, k = i - bc2 * 255;
        float xv = (float)k * (1.0f / 255.0f);
        float xi = floorf(xv * 9.0f);
        xi = fminf(fmaxf(xi, 0.f), 8.f);
        int ix = (int)xi;
        float xf = xv - xi * STEP_F;
        const float* cf = fcoef[bc2];
        splines_out[i] = fmaf(fmaf(fmaf(cf[ix], xf, cf[9 + ix]), xf, cf[18 + ix]), xf, cf[27 + ix]);
    }
}

// ---------------------------------------------------------------------------
// Apply spline to full-res x. One block = 1024 consecutive floats.
// ---------------------------------------------------------------------------
__global__ __launch_bounds__(256) void apply_k(const float* __restrict__ x,
                                               const float* __restrict__ coeff,
                                               float* __restrict__ out)
{
    __shared__ float cf[36];
    const int blk = blockIdx.x;
    const int plane = blk >> 10;
    const int t = threadIdx.x;
    if (t < 36) cf[t] = coeff[plane * 36 + t];
    __syncthreads();

    size_t base = (size_t)blk * 1024 + (size_t)t * 4;
    float4 v = *(const float4*)(x + base);
    f32x4 o;
    #pragma unroll
    for (int k = 0; k < 4; k++) {
        float xv = (k == 0) ? v.x : (k == 1) ? v.y : (k == 2) ? v.z : v.w;
        float xi = floorf(xv * 9.0f);
        xi = fminf(fmaxf(xi, 0.f), 8.f);
        int ix = (int)xi;
        float xf = xv - xi * STEP_F;
        o[k] = fmaf(fmaf(fmaf(cf[ix], xf, cf[9 + ix]), xf, cf[18 + ix]), xf, cf[27 + ix]);
    }
    __builtin_nontemporal_store(o, (f32x4*)(out + base));
}

// ---------------------------------------------------------------------------
extern "C" void kernel_launch(void* const* d_in, const int* in_sizes, int n_in,
                              void* d_out, int out_size, void* d_ws, size_t ws_size,
                              hipStream_t stream) {
    (void)in_sizes; (void)n_in; (void)out_size; (void)ws_size;

    const float* x    = (const float*)d_in[0];
    const float* w1   = (const float*)d_in[1];
    const float* b1   = (const float*)d_in[2];
    const float* w2   = (const float*)d_in[3];
    const float* b2   = (const float*)d_in[4];
    const float* g2   = (const float*)d_in[5];
    const float* be2  = (const float*)d_in[6];
    const float* w3   = (const float*)d_in[7];
    const float* b3   = (const float*)d_in[8];
    const float* g3   = (const float*)d_in[9];
    const float* be3  = (const float*)d_in[10];
    const float* w4   = (const float*)d_in[11];
    const float* b4   = (const float*)d_in[12];
    const float* g4   = (const float*)d_in[13];
    const float* be4  = (const float*)d_in[14];
    const float* w5   = (const float*)d_in[15];
    const float* b5   = (const float*)d_in[16];
    const float* g5   = (const float*)d_in[17];
    const float* be5  = (const float*)d_in[18];
    const float* fc1w = (const float*)d_in[19];
    const float* fc1b = (const float*)d_in[20];
    const float* fc2w = (const float*)d_in[21];
    const float* fc2b = (const float*)d_in[22];

    float* out = (float*)d_out;
    float* wsf = (float*)d_ws;

    // ws: per-block partials (fully overwritten every call); the barrier and
    // finale counters are zeroed by resize_k block 0 each call.
    float* pS2 = wsf + 0;       // [8*16*16] = 2048
    float* pQ2 = wsf + 2048;
    float* pS3 = wsf + 4096;    // [8*32*4]  = 1024
    float* pQ3 = wsf + 5120;
    float* pS4 = wsf + 6144;    // [8*64*2]  = 1024
    float* pQ4 = wsf + 7168;
    float* pS5 = wsf + 8192;    // [8*128]   = 1024  (spatial sums for fc)
    float* pQ5 = wsf + 9216;
    float* coeff = wsf + 10240; // [24*36]
    unsigned* ctr = (unsigned*)(wsf + 11264);  // [3]

    // big intermediates in d_out (overwritten by apply_k)
    float* sm  = out;                  // 24*256*256  = 1572864
    float* h1  = out + 1572864;        // 8*8*127*127 = 1032256
    float* h2  = out + 2605120;        // 8*16*63*63  =  508032
    float* h3  = out + 3113152;        // 8*32*31*31  =  246016
    float* h4  = out + 3359168;        // 8*64*15*15  =  115200

    resize_k<<<1536, 256, 0, stream>>>(x, sm, ctr);

    // conv1: 3->8, 256->127
    conv_k<3, 8, 256, 127, 1, 256, 1, 1, false, false, true>
        <<<dim3(64, 32), 256, 0, stream>>>(sm, w1, b1, nullptr, nullptr,
                                           nullptr, nullptr, 0.f,
                                           h1, nullptr, nullptr);
    // conv2: 8->16, 127->63  (writes 16-tile partials)
    conv_k<8, 16, 127, 63, 1, 256, 1, 16, false, true, true>
        <<<dim3(16, 64), 256, 0, stream>>>(h1, w2, b2, nullptr, nullptr,
                                           nullptr, nullptr, 0.f,
                                           h2, pS2, pQ2);
    // conv3+conv4+conv5+fc fused (512 co-resident blocks, 2 barriers, finale)
    c345_k<<<512, 256, 0, stream>>>(h2,
                                    w3, b3, g2, be2, pS2, pQ2,
                                    h3, pS3, pQ3,
                                    w4, b4, g3, be3,
                                    h4, pS4, pQ4,
                                    w5, b5, g4, be4,
                                    pS5, pQ5,
                                    g5, be5, fc1w, fc1b, fc2w, fc2b,
                                    coeff, out + SPLINE_OFF, ctr);

    apply_k<<<24576, 256, 0, stream>>>(x, coeff, out);
}

// Round 12
// 131.172 us; speedup vs baseline: 1.5231x; 1.5231x over previous
//
#include <hip/hip_runtime.h>

#define SPLINE_OFF 25165824   // splines output offset (6120 floats follow)
#define STEP_F (1.0f/9.0f)

typedef float f32x4 __attribute__((ext_vector_type(4)));

// ---------------------------------------------------------------------------
// Resize: jax.image.resize bilinear antialias 1024->256 (scale .25), separable
// triangle kernel {1,3,5,7,7,5,3,1}/8 at stride 4, renormalized at edges.
// Each block produces FOUR output rows of one plane (reads 20 rows once).
// Block 0 zeroes the conv5 finale counter (stream-ordered before conv5fc).
// ---------------------------------------------------------------------------
__global__ __launch_bounds__(256) void resize_k(const float* __restrict__ x,
                                                float* __restrict__ sm,
                                                unsigned* __restrict__ ctr) {
    __shared__ float vs[4][1024];
    const int blk = blockIdx.x;          // 24*64
    const int plane = blk >> 6;
    const int orA = (blk & 63) * 4;      // output rows orA..orA+3
    const int t = threadIdx.x;
    if (blk == 0 && t == 0) ctr[0] = 0u;

    const float W[8] = {0.125f,0.375f,0.625f,0.875f,0.875f,0.625f,0.375f,0.125f};
    const float* p = x + (size_t)plane * 1048576 + t * 4;
    const int rb = 4 * orA - 2;

    float acc[4][4];
    #pragma unroll
    for (int o = 0; o < 4; o++)
        #pragma unroll
        for (int c = 0; c < 4; c++) acc[o][c] = 0.f;

    if (rb >= 0 && rb + 19 <= 1023) {
        #pragma unroll
        for (int k = 0; k < 20; k++) {
            const float4 v = *(const float4*)(p + (size_t)(rb + k) * 1024);
            #pragma unroll
            for (int o = 0; o < 4; o++) {
                const int j = k - 4 * o;
                if (j >= 0 && j < 8) {
                    const float w = W[j] * 0.25f;
                    acc[o][0] = fmaf(v.x, w, acc[o][0]);
                    acc[o][1] = fmaf(v.y, w, acc[o][1]);
                    acc[o][2] = fmaf(v.z, w, acc[o][2]);
                    acc[o][3] = fmaf(v.w, w, acc[o][3]);
                }
            }
        }
    } else {
        #pragma unroll
        for (int o = 0; o < 4; o++) {
            const int r0 = 4 * (orA + o) - 2;
            float bx=0.f,by=0.f,bz=0.f,bw=0.f,wsum=0.f;
            #pragma unroll
            for (int k = 0; k < 8; k++) {
                const int r = r0 + k;
                if (r >= 0 && r < 1024) {
                    const float4 v = *(const float4*)(p + (size_t)r * 1024);
                    bx = fmaf(v.x, W[k], bx); by = fmaf(v.y, W[k], by);
                    bz = fmaf(v.z, W[k], bz); bw = fmaf(v.w, W[k], bw);
                    wsum += W[k];
                }
            }
            const float inv = 1.f / wsum;
            acc[o][0]=bx*inv; acc[o][1]=by*inv; acc[o][2]=bz*inv; acc[o][3]=bw*inv;
        }
    }
    #pragma unroll
    for (int o = 0; o < 4; o++) {
        vs[o][4*t+0]=acc[o][0]; vs[o][4*t+1]=acc[o][1];
        vs[o][4*t+2]=acc[o][2]; vs[o][4*t+3]=acc[o][3];
    }
    __syncthreads();

    const int c0 = 4 * t - 2;
    #pragma unroll
    for (int o = 0; o < 4; o++) {
        float a = 0.f;
        if (c0 >= 0 && c0 + 7 <= 1023) {
            #pragma unroll
            for (int k = 0; k < 8; k++)
                a = fmaf(vs[o][c0 + k], W[k] * 0.25f, a);
        } else {
            float wsum = 0.f;
            #pragma unroll
            for (int k = 0; k < 8; k++) {
                const int c = c0 + k;
                if (c >= 0 && c < 1024) { a = fmaf(vs[o][c], W[k], a); wsum += W[k]; }
            }
            a /= wsum;
        }
        sm[((size_t)plane * 256 + orA + o) * 256 + t] = a;
    }
}

// ---------------------------------------------------------------------------
// Direct 3x3 stride-2 VALID conv + bias + ReLU.  No atomics:
//  - INBN: previous layer's BN derived by reducing its per-block partials,
//    folded into staged weights: conv(sc*x+sh) = conv_{w*sc}(x) + C.
//  - STATS: block-reduced per-channel sum/sumsq -> unique partial slot.
//  - NCO=2 fixed; CISPLIT-way ci-split with LDS reduce.
// Grid: (NTOUT, B * COUT/2). Block: PIX*CISPLIT threads.
// ---------------------------------------------------------------------------
template<int CIN, int COUT, int INW, int OUTW, int CISPLIT, int PIX,
         int NTPREV, int NTOUT, bool INBN, bool STATS, bool WRITE>
__global__ __launch_bounds__(PIX * CISPLIT) void conv_k(
    const float* __restrict__ in, const float* __restrict__ w,
    const float* __restrict__ bias,
    const float* __restrict__ gam, const float* __restrict__ be,
    const float* __restrict__ pS, const float* __restrict__ pQ, float invN,
    float* __restrict__ out,
    float* __restrict__ pSo, float* __restrict__ pQo)
{
    constexpr int BLOCK = PIX * CISPLIT;
    constexpr int CPS = CIN / CISPLIT;
    constexpr int COG = COUT / 2;

    __shared__ float wsm[2][CIN * 9];
    __shared__ float scs[CIN], shs[CIN];
    __shared__ float wrow[2][CIN];
    __shared__ float cadd[2];
    __shared__ float part[CISPLIT][PIX][2];
    __shared__ float red[2][2][PIX / 64];
    __shared__ float sredS[BLOCK], sredQ[BLOCK];

    const int tid = threadIdx.x;
    const int p   = tid & (PIX - 1);
    const int cs  = tid / PIX;
    const int bc  = blockIdx.y;
    const int b   = bc / COG;
    const int co0 = (bc % COG) * 2;

    if constexpr (INBN) {
        constexpr int GRP = BLOCK / CIN;
        constexpr int TERMS = 8 * NTPREV;
        const int ci = tid % CIN;
        const int gi = tid / CIN;
        float s = 0.f, q = 0.f;
        for (int j = gi; j < TERMS; j += GRP) {
            const int bb = j / NTPREV, tl = j - bb * NTPREV;
            const int a = (bb * CIN + ci) * NTPREV + tl;
            s += pS[a]; q += pQ[a];
        }
        sredS[gi * CIN + ci] = s;
        sredQ[gi * CIN + ci] = q;
        __syncthreads();
        if (tid < CIN) {
            float ts = 0.f, tq = 0.f;
            #pragma unroll
            for (int g2 = 0; g2 < GRP; g2++) {
                ts += sredS[g2 * CIN + tid];
                tq += sredQ[g2 * CIN + tid];
            }
            const float m = ts * invN;
            const float v = tq * invN - m * m;
            const float sc = gam[tid] * rsqrtf(v + 1e-5f);
            scs[tid] = sc;
            shs[tid] = be[tid] - m * sc;
        }
        __syncthreads();
    }

    for (int i = tid; i < 2 * CIN * 9; i += BLOCK) {
        const int n = i / (CIN * 9), r = i - n * (CIN * 9), ci = r / 9;
        const float wv = w[(co0 + n) * CIN * 9 + r];
        wsm[n][r] = INBN ? wv * scs[ci] : wv;
    }
    if constexpr (INBN) {
        for (int i = tid; i < 2 * CIN; i += BLOCK) {
            const int n = i / CIN, ci = i - n * CIN;
            const float* wp = w + ((co0 + n) * CIN + ci) * 9;
            float s = 0.f;
            #pragma unroll
            for (int k = 0; k < 9; k++) s += wp[k];
            wrow[n][ci] = s;
        }
    }
    __syncthreads();
    if (tid < 2) {
        float c = bias[co0 + tid];
        if constexpr (INBN) {
            for (int ci = 0; ci < CIN; ci++) c = fmaf(wrow[tid][ci], shs[ci], c);
        }
        cadd[tid] = c;
    }
    __syncthreads();

    const int npix = OUTW * OUTW;
    const int pg = blockIdx.x * PIX + p;
    float a0 = 0.f, a1 = 0.f;
    if (pg < npix) {
        const int oh = pg / OUTW, ow = pg - oh * OUTW;
        const float* ib = in + ((size_t)(b * CIN) + cs * CPS) * (INW * INW)
                             + (size_t)(2 * oh) * INW + 2 * ow;
        #pragma unroll 4
        for (int ci = 0; ci < CPS; ci++) {
            const float* ip = ib + (size_t)ci * (INW * INW);
            const int cw = (cs * CPS + ci) * 9;
            #pragma unroll
            for (int kh = 0; kh < 3; kh++) {
                const float* r = ip + kh * INW;
                #pragma unroll
                for (int kw = 0; kw < 3; kw++) {
                    const float xv = r[kw];
                    a0 = fmaf(xv, wsm[0][cw + kh * 3 + kw], a0);
                    a1 = fmaf(xv, wsm[1][cw + kh * 3 + kw], a1);
                }
            }
        }
    }

    float v0 = 0.f, v1 = 0.f;
    if constexpr (CISPLIT > 1) {
        part[cs][p][0] = a0; part[cs][p][1] = a1;
        __syncthreads();
    }
    if (cs == 0) {
        float s0 = a0, s1 = a1;
        if constexpr (CISPLIT > 1) {
            #pragma unroll
            for (int q = 1; q < CISPLIT; q++) { s0 += part[q][p][0]; s1 += part[q][p][1]; }
        }
        if (pg < npix) {
            v0 = fmaxf(s0 + cadd[0], 0.f);
            v1 = fmaxf(s1 + cadd[1], 0.f);
            if constexpr (WRITE) {
                out[(size_t)(b * COUT + co0) * npix + pg] = v0;
                out[(size_t)(b * COUT + co0 + 1) * npix + pg] = v1;
            }
        }
    }

    if constexpr (STATS) {
        if (cs == 0) {
            float sA = v0, qA = v0 * v0, sB = v1, qB = v1 * v1;
            #pragma unroll
            for (int off = 32; off > 0; off >>= 1) {
                sA += __shfl_down(sA, off); qA += __shfl_down(qA, off);
                sB += __shfl_down(sB, off); qB += __shfl_down(qB, off);
            }
            if ((tid & 63) == 0) {
                red[0][0][tid >> 6] = sA; red[0][1][tid >> 6] = qA;
                red[1][0][tid >> 6] = sB; red[1][1][tid >> 6] = qB;
            }
        }
        __syncthreads();
        if (tid == 0) {
            float tsA = 0.f, tqA = 0.f, tsB = 0.f, tqB = 0.f;
            #pragma unroll
            for (int i = 0; i < PIX / 64; i++) {
                tsA += red[0][0][i]; tqA += red[0][1][i];
                tsB += red[1][0][i]; tqB += red[1][1][i];
            }
            pSo[(b * COUT + co0) * NTOUT + blockIdx.x] = tsA;
            pQo[(b * COUT + co0) * NTOUT + blockIdx.x] = tqA;
            pSo[(b * COUT + co0 + 1) * NTOUT + blockIdx.x] = tsB;
            pQo[(b * COUT + co0 + 1) * NTOUT + blockIdx.x] = tqB;
        }
    }
}

// ---------------------------------------------------------------------------
// conv5 (64->128, 15->7, BN4 folded, ci-split 4, stats only) fused with the
// fc/spline tail via a LAST-BLOCK FINALE (one atomicAdd per block; the block
// seeing old==511 runs BN5 -> mean -> fc1 -> fc2 -> Thomas -> splines).
// Counter zeroed by resize_k block 0 every call. Grid: 512 x 256.
// ---------------------------------------------------------------------------
__global__ __launch_bounds__(256) void conv5fc_k(
    const float* __restrict__ in, const float* __restrict__ w,
    const float* __restrict__ bias,
    const float* __restrict__ gam, const float* __restrict__ be,
    const float* __restrict__ pS, const float* __restrict__ pQ,
    float* __restrict__ pS5, float* __restrict__ pQ5,
    const float* __restrict__ g5, const float* __restrict__ be5,
    const float* __restrict__ fc1w, const float* __restrict__ fc1b,
    const float* __restrict__ fc2w, const float* __restrict__ fc2b,
    float* __restrict__ coeff_out, float* __restrict__ splines_out,
    unsigned* __restrict__ ctr)
{
    constexpr int CIN = 64, COUT = 128, INW = 15, OUTW = 7;
    constexpr int CISPLIT = 4, PIX = 64, BLOCK = 256;
    constexpr int CPS = CIN / CISPLIT;
    constexpr int COG = COUT / 2;
    const float invN = 1.0f / 1800.0f;

    __shared__ float wsm[2][CIN * 9];
    __shared__ float scs[CIN], shs[CIN];
    __shared__ float wrow[2][CIN];
    __shared__ float cadd[2];
    __shared__ float part[CISPLIT][PIX][2];
    __shared__ float sredS[BLOCK], sredQ[BLOCK];
    __shared__ unsigned lastFlag;
    __shared__ float fsc5[128], fsh5[128];
    __shared__ float fch[1024], fh1[1024];
    __shared__ float fysn[240];
    __shared__ float fcoef[24][36];

    const int tid = threadIdx.x;
    const int p   = tid & (PIX - 1);
    const int cs  = tid / PIX;
    const int bc  = blockIdx.x;          // 0..511
    const int b   = bc / COG;
    const int co0 = (bc % COG) * 2;

    {
        constexpr int GRP = BLOCK / CIN;   // 4
        const int ci = tid % CIN;
        const int gi = tid / CIN;
        float s = 0.f, q = 0.f;
        for (int j = gi; j < 8; j += GRP) {
            const int a = j * CIN + ci;
            s += pS[a]; q += pQ[a];
        }
        sredS[gi * CIN + ci] = s;
        sredQ[gi * CIN + ci] = q;
        __syncthreads();
        if (tid < CIN) {
            float ts = 0.f, tq = 0.f;
            #pragma unroll
            for (int g2 = 0; g2 < GRP; g2++) {
                ts += sredS[g2 * CIN + tid];
                tq += sredQ[g2 * CIN + tid];
            }
            const float m = ts * invN;
            const float v = tq * invN - m * m;
            const float sc = gam[tid] * rsqrtf(v + 1e-5f);
            scs[tid] = sc;
            shs[tid] = be[tid] - m * sc;
        }
        __syncthreads();
    }

    for (int i = tid; i < 2 * CIN * 9; i += BLOCK) {
        const int n = i / (CIN * 9), r = i - n * (CIN * 9), ci = r / 9;
        wsm[n][r] = w[(co0 + n) * CIN * 9 + r] * scs[ci];
    }
    for (int i = tid; i < 2 * CIN; i += BLOCK) {
        const int n = i / CIN, ci = i - n * CIN;
        const float* wp = w + ((co0 + n) * CIN + ci) * 9;
        float s = 0.f;
        #pragma unroll
        for (int k = 0; k < 9; k++) s += wp[k];
        wrow[n][ci] = s;
    }
    __syncthreads();
    if (tid < 2) {
        float c = bias[co0 + tid];
        for (int ci = 0; ci < CIN; ci++) c = fmaf(wrow[tid][ci], shs[ci], c);
        cadd[tid] = c;
    }
    __syncthreads();

    float a0 = 0.f, a1 = 0.f;
    if (p < 49) {
        const int oh = p / OUTW, ow = p - oh * OUTW;
        const float* ib = in + ((size_t)(b * CIN) + cs * CPS) * (INW * INW)
                             + (size_t)(2 * oh) * INW + 2 * ow;
        #pragma unroll 4
        for (int ci = 0; ci < CPS; ci++) {
            const float* ip = ib + (size_t)ci * (INW * INW);
            const int cw = (cs * CPS + ci) * 9;
            #pragma unroll
            for (int kh = 0; kh < 3; kh++) {
                const float* r = ip + kh * INW;
                #pragma unroll
                for (int kw = 0; kw < 3; kw++) {
                    const float xv = r[kw];
                    a0 = fmaf(xv, wsm[0][cw + kh * 3 + kw], a0);
                    a1 = fmaf(xv, wsm[1][cw + kh * 3 + kw], a1);
                }
            }
        }
    }

    part[cs][p][0] = a0; part[cs][p][1] = a1;
    __syncthreads();
    if (cs == 0) {
        float s0 = a0 + part[1][p][0] + part[2][p][0] + part[3][p][0];
        float s1 = a1 + part[1][p][1] + part[2][p][1] + part[3][p][1];
        float v0 = 0.f, v1 = 0.f;
        if (p < 49) {
            v0 = fmaxf(s0 + cadd[0], 0.f);
            v1 = fmaxf(s1 + cadd[1], 0.f);
        }
        float sA = v0, qA = v0 * v0, sB = v1, qB = v1 * v1;
        #pragma unroll
        for (int off = 32; off > 0; off >>= 1) {
            sA += __shfl_down(sA, off); qA += __shfl_down(qA, off);
            sB += __shfl_down(sB, off); qB += __shfl_down(qB, off);
        }
        if (p == 0) {
            pS5[b * COUT + co0] = sA;
            pQ5[b * COUT + co0] = qA;
            pS5[b * COUT + co0 + 1] = sB;
            pQ5[b * COUT + co0 + 1] = qB;
        }
    }
    __syncthreads();

    if (tid == 0) {
        __threadfence();
        unsigned old = atomicAdd(ctr, 1u);
        lastFlag = (old == 511u) ? 1u : 0u;
    }
    __syncthreads();
    if (lastFlag == 0u) return;
    __threadfence();

    const int t = tid;
    if (t < 128) {
        float sv = 0.f, qv = 0.f;
        #pragma unroll
        for (int bb = 0; bb < 8; bb++) { sv += pS5[bb * 128 + t]; qv += pQ5[bb * 128 + t]; }
        float m = sv * (1.f / 392.f);
        float v = qv * (1.f / 392.f) - m * m;
        float sc = g5[t] * rsqrtf(v + 1e-5f);
        fsc5[t] = sc;
        fsh5[t] = be5[t] - m * sc;
    }
    __syncthreads();

    for (int i = t; i < 1024; i += 256) {
        int c = i & 127;
        fch[i] = fmaf(fsc5[c], pS5[i] * (1.f / 49.f), fsh5[c]);
    }
    __syncthreads();

    for (int i = t; i < 1024; i += 256) {
        int bb = i >> 7, j = i & 127;
        float acc = fc1b[j];
        for (int c = 0; c < 128; c++)
            acc = fmaf(fch[(bb << 7) + c], fc1w[(j << 7) + c], acc);
        fh1[i] = fmaxf(acc, 0.f);
    }
    __syncthreads();

    if (t < 240) {
        int bb = t / 30, k = t % 30;
        float acc = fc2b[k];
        for (int j = 0; j < 128; j++)
            acc = fmaf(fh1[(bb << 7) + j], fc2w[(k << 7) + j], acc);
        fysn[t] = acc + (float)(k % 10) * STEP_F;
    }
    __syncthreads();

    if (t < 24) {
        float y[10];
        #pragma unroll
        for (int i = 0; i < 10; i++) y[i] = fysn[t * 10 + i];
        float rhs[9], cp[9], dp[9];
        #pragma unroll
        for (int i = 1; i <= 8; i++)
            rhs[i] = 486.f * (y[i - 1] - 2.f * y[i] + y[i + 1]);
        cp[1] = 0.25f; dp[1] = rhs[1] * 0.25f;
        #pragma unroll
        for (int i = 2; i <= 8; i++) {
            float m = 1.f / (4.f - cp[i - 1]);
            cp[i] = m;
            dp[i] = (rhs[i] - dp[i - 1]) * m;
        }
        float M[10];
        M[0] = 0.f; M[9] = 0.f;
        M[8] = dp[8];
        #pragma unroll
        for (int i = 7; i >= 1; i--) M[i] = dp[i] - cp[i] * M[i + 1];
        #pragma unroll
        for (int i = 0; i < 9; i++) {
            float a = (M[i + 1] - M[i]) * 1.5f;
            float bb2 = M[i] * 0.5f;
            float cc = (y[i + 1] - y[i]) * 9.f - (M[i + 1] + 2.f * M[i]) * (STEP_F / 6.f);
            float dd = y[i];
            fcoef[t][i] = a; fcoef[t][9 + i] = bb2; fcoef[t][18 + i] = cc; fcoef[t][27 + i] = dd;
            coeff_out[t * 36 + i] = a;
            coeff_out[t * 36 + 9 + i] = bb2;
            coeff_out[t * 36 + 18 + i] = cc;
            coeff_out[t * 36 + 27 + i] = dd;
        }
    }
    __syncthreads();

    for (int i = t; i < 24 * 255; i += 256) {
        int bc2 = i / 255, k = i - bc2 * 255;
        float xv = (float)k * (1.0f / 255.0f);
        float xi = floorf(xv * 9.0f);
        xi = fminf(fmaxf(xi, 0.f), 8.f);
        int ix = (int)xi;
        float xf = xv - xi * STEP_F;
        const float* cf = fcoef[bc2];
        splines_out[i] = fmaf(fmaf(fmaf(cf[ix], xf, cf[9 + ix]), xf, cf[18 + ix]), xf, cf[27 + ix]);
    }
}

// ---------------------------------------------------------------------------
// Apply spline to full-res x. One block = 1024 consecutive floats.
// ---------------------------------------------------------------------------
__global__ __launch_bounds__(256) void apply_k(const float* __restrict__ x,
                                               const float* __restrict__ coeff,
                                               float* __restrict__ out)
{
    __shared__ float cf[36];
    const int blk = blockIdx.x;
    const int plane = blk >> 10;
    const int t = threadIdx.x;
    if (t < 36) cf[t] = coeff[plane * 36 + t];
    __syncthreads();

    size_t base = (size_t)blk * 1024 + (size_t)t * 4;
    float4 v = *(const float4*)(x + base);
    f32x4 o;
    #pragma unroll
    for (int k = 0; k < 4; k++) {
        float xv = (k == 0) ? v.x : (k == 1) ? v.y : (k == 2) ? v.z : v.w;
        float xi = floorf(xv * 9.0f);
        xi = fminf(fmaxf(xi, 0.f), 8.f);
        int ix = (int)xi;
        float xf = xv - xi * STEP_F;
        o[k] = fmaf(fmaf(fmaf(cf[ix], xf, cf[9 + ix]), xf, cf[18 + ix]), xf, cf[27 + ix]);
    }
    __builtin_nontemporal_store(o, (f32x4*)(out + base));
}

// ---------------------------------------------------------------------------
extern "C" void kernel_launch(void* const* d_in, const int* in_sizes, int n_in,
                              void* d_out, int out_size, void* d_ws, size_t ws_size,
                              hipStream_t stream) {
    (void)in_sizes; (void)n_in; (void)out_size; (void)ws_size;

    const float* x    = (const float*)d_in[0];
    const float* w1   = (const float*)d_in[1];
    const float* b1   = (const float*)d_in[2];
    const float* w2   = (const float*)d_in[3];
    const float* b2   = (const float*)d_in[4];
    const float* g2   = (const float*)d_in[5];
    const float* be2  = (const float*)d_in[6];
    const float* w3   = (const float*)d_in[7];
    const float* b3   = (const float*)d_in[8];
    const float* g3   = (const float*)d_in[9];
    const float* be3  = (const float*)d_in[10];
    const float* w4   = (const float*)d_in[11];
    const float* b4   = (const float*)d_in[12];
    const float* g4   = (const float*)d_in[13];
    const float* be4  = (const float*)d_in[14];
    const float* w5   = (const float*)d_in[15];
    const float* b5   = (const float*)d_in[16];
    const float* g5   = (const float*)d_in[17];
    const float* be5  = (const float*)d_in[18];
    const float* fc1w = (const float*)d_in[19];
    const float* fc1b = (const float*)d_in[20];
    const float* fc2w = (const float*)d_in[21];
    const float* fc2b = (const float*)d_in[22];

    float* out = (float*)d_out;
    float* wsf = (float*)d_ws;

    // ws: per-block partials (fully overwritten every call; the only atomic
    // is the conv5 finale counter, zeroed by resize_k block 0 each call)
    float* pS2 = wsf + 0;      // [8*16*16] = 2048
    float* pQ2 = wsf + 2048;
    float* pS3 = wsf + 4096;   // [8*32*4]  = 1024
    float* pQ3 = wsf + 5120;
    float* pS4 = wsf + 6144;   // [8*64*1]  = 512
    float* pQ4 = wsf + 6656;
    float* pS5 = wsf + 7168;   // [8*128]   = 1024  (spatial sums for fc)
    float* pQ5 = wsf + 8192;
    float* coeff = wsf + 9216; // [24*36]
    unsigned* ctr = (unsigned*)(wsf + 10240);

    // big intermediates in d_out (overwritten by apply_k)
    float* sm  = out;                  // 24*256*256  = 1572864
    float* h1  = out + 1572864;        // 8*8*127*127 = 1032256
    float* h2  = out + 2605120;        // 8*16*63*63  =  508032
    float* h3  = out + 3113152;        // 8*32*31*31  =  246016
    float* h4  = out + 3359168;        // 8*64*15*15  =  115200

    resize_k<<<1536, 256, 0, stream>>>(x, sm, ctr);

    // conv1: 3->8, 256->127
    conv_k<3, 8, 256, 127, 1, 256, 1, 1, false, false, true>
        <<<dim3(64, 32), 256, 0, stream>>>(sm, w1, b1, nullptr, nullptr,
                                           nullptr, nullptr, 0.f,
                                           h1, nullptr, nullptr);
    // conv2: 8->16, 127->63  (writes 16-tile partials)
    conv_k<8, 16, 127, 63, 1, 256, 1, 16, false, true, true>
        <<<dim3(16, 64), 256, 0, stream>>>(h1, w2, b2, nullptr, nullptr,
                                           nullptr, nullptr, 0.f,
                                           h2, pS2, pQ2);
    // conv3: 16->32, 63->31  (BN2 from pS2/pQ2; writes 4-tile partials)
    conv_k<16, 32, 63, 31, 1, 256, 16, 4, true, true, true>
        <<<dim3(4, 128), 256, 0, stream>>>(h2, w3, b3, g2, be2,
                                           pS2, pQ2, 1.0f / 31752.0f,
                                           h3, pS3, pQ3);
    // conv4: 32->64, 31->15  (BN3; ci-split 2; 1-tile partials)
    conv_k<32, 64, 31, 15, 2, 256, 4, 1, true, true, true>
        <<<dim3(1, 256), 512, 0, stream>>>(h3, w4, b4, g3, be3,
                                           pS3, pQ3, 1.0f / 7688.0f,
                                           h4, pS4, pQ4);
    // conv5 + fc/spline tail (last-block finale)
    conv5fc_k<<<512, 256, 0, stream>>>(h4, w5, b5, g4, be4,
                                       pS4, pQ4, pS5, pQ5,
                                       g5, be5, fc1w, fc1b, fc2w, fc2b,
                                       coeff, out + SPLINE_OFF, ctr);

    apply_k<<<24576, 256, 0, stream>>>(x, coeff, out);
}